// Round 1
// baseline (104.547 us; speedup 1.0000x reference)
//
#include <hip/hip_runtime.h>
#include <hip/hip_bf16.h>

typedef __attribute__((ext_vector_type(8))) short short8;
typedef __attribute__((ext_vector_type(4))) float f32x4;

#define NROW 8192
#define FDIM 64
#define INDIM 128
#define BK 64
#define LDP 72   // padded LDS row stride in bf16 elements (72*2B=144B -> conflict-free-ish b128 reads)

// ---------------- Kernel 1: Wh = h@W (f32), WhT (bf16, f-major), s = Wh@a1, d = Wh@a2 ----------------
__global__ __launch_bounds__(256) void k_wh(const float* __restrict__ h,
                                            const float* __restrict__ W,
                                            const float* __restrict__ a,
                                            __hip_bfloat16* __restrict__ WhT,
                                            float* __restrict__ s,
                                            float* __restrict__ d) {
  const int i = blockIdx.x * 4 + (threadIdx.x >> 6);  // row, one wave per row
  const int f = threadIdx.x & 63;                     // feature, lane
  const float* hrow = h + (size_t)i * INDIM;
  float acc = 0.f;
#pragma unroll 8
  for (int k = 0; k < INDIM; ++k) acc = fmaf(hrow[k], W[k * FDIM + f], acc);
  WhT[(size_t)f * NROW + i] = __float2bfloat16(acc);
  float p1 = acc * a[f];
  float p2 = acc * a[FDIM + f];
#pragma unroll
  for (int m = 32; m; m >>= 1) {
    p1 += __shfl_xor(p1, m, 64);
    p2 += __shfl_xor(p2, m, 64);
  }
  if (f == 0) { s[i] = p1; d[i] = p2; }
}

// ---------------- Kernel 2: dmax = max(d) ----------------
__global__ __launch_bounds__(256) void k_dmax(const float* __restrict__ d,
                                              float* __restrict__ dmax) {
  __shared__ float red[256];
  float m = -3.4e38f;
  for (int j = threadIdx.x; j < NROW; j += 256) m = fmaxf(m, d[j]);
  red[threadIdx.x] = m;
  __syncthreads();
  for (int k = 128; k; k >>= 1) {
    if ((int)threadIdx.x < k) red[threadIdx.x] = fmaxf(red[threadIdx.x], red[threadIdx.x + k]);
    __syncthreads();
  }
  if (threadIdx.x == 0) *dmax = red[0];
}

// ---------------- Kernel 3: fused masked-softmax-attention, partial accumulate ----------------
// grid = 128*splits blocks, 256 threads (4 waves). Block = 64 rows x (8192/splits) j-range.
__global__ __launch_bounds__(256) void k_main(const int* __restrict__ adj,
                                              const __hip_bfloat16* __restrict__ WhT,
                                              const float* __restrict__ sArr,
                                              const float* __restrict__ dArr,
                                              const float* __restrict__ dmaxPtr,
                                              float* __restrict__ accp,
                                              float* __restrict__ Zp,
                                              int splits) {
  __shared__ __hip_bfloat16 P[64 * LDP];   // attention-weight tile [64 rows][BK j]
  __shared__ __hip_bfloat16 BT[64 * LDP];  // WhT tile [64 f][BK j]

  const int t = threadIdx.x;
  const int nchunk = (NROW / BK) / splits;
  const int tile = blockIdx.x / splits;
  const int split = blockIdx.x - tile * splits;
  const int row0 = tile * 64;
  const int j0 = split * nchunk * BK;
  const float dmax = *dmaxPtr;

  // P-compute assignment: thread handles rows (t>>5)+8*rr (rr=0..7), j-offsets 2*(t&31)+{0,1}
  const int rb = t >> 5;
  const int jo = 2 * (t & 31);
  float sreg[8], mreg[8], zacc[8];
#pragma unroll
  for (int rr = 0; rr < 8; ++rr) {
    float sv = sArr[row0 + rb + 8 * rr];
    sreg[rr] = sv;
    float x = sv + dmax;
    mreg[rr] = (x >= 0.f) ? x : 0.01f * x;  // m_i = leaky(s_i + dmax) >= all masked logits
    zacc[rr] = 0.f;
  }

  // MFMA assignment: wave w -> rows 32*(w&1)+0..31, cols 32*(w>>1)+0..31
  const int w = t >> 6, l = t & 63;
  const int rwave = 32 * (w & 1);
  const int nwave = 32 * (w >> 1);
  f32x4 acc00 = {0.f, 0.f, 0.f, 0.f}, acc01 = acc00, acc10 = acc00, acc11 = acc00;

  // B staging assignment: thread t stages WhT[f=t>>2][ (t&3)*16 .. +16 ]
  const int bfr = t >> 2, bj = (t & 3) * 16;

  int2 av[8];
  float2 dv;
  uint4 bv0, bv1;
  // prefetch chunk 0
  {
    const int jb = j0;
    dv = *(const float2*)(dArr + jb + jo);
#pragma unroll
    for (int rr = 0; rr < 8; ++rr)
      av[rr] = *(const int2*)(adj + (size_t)(row0 + rb + 8 * rr) * NROW + jb + jo);
    const uint4* bs = (const uint4*)(WhT + (size_t)bfr * NROW + jb + bj);
    bv0 = bs[0]; bv1 = bs[1];
  }

  for (int c = 0; c < nchunk; ++c) {
    // ---- phase 1: compute P tile + stage B tile ----
#pragma unroll
    for (int rr = 0; rr < 8; ++rr) {
      const int r = rb + 8 * rr;
      float x0 = sreg[rr] + dv.x; x0 = (x0 >= 0.f) ? x0 : 0.01f * x0;
      float x1 = sreg[rr] + dv.y; x1 = (x1 >= 0.f) ? x1 : 0.01f * x1;
      float w0 = (av[rr].x > 0) ? __expf(x0 - mreg[rr]) : 0.f;
      float w1 = (av[rr].y > 0) ? __expf(x1 - mreg[rr]) : 0.f;
      zacc[rr] += w0 + w1;
      __hip_bfloat162 pv;
      pv.x = __float2bfloat16(w0);
      pv.y = __float2bfloat16(w1);
      *(__hip_bfloat162*)&P[r * LDP + jo] = pv;
    }
    *(uint4*)&BT[bfr * LDP + bj] = bv0;
    *(uint4*)&BT[bfr * LDP + bj + 8] = bv1;
    __syncthreads();

    // ---- prefetch next chunk's adj/d/B during MFMA phase ----
    if (c + 1 < nchunk) {
      const int jb = j0 + (c + 1) * BK;
      dv = *(const float2*)(dArr + jb + jo);
#pragma unroll
      for (int rr = 0; rr < 8; ++rr)
        av[rr] = *(const int2*)(adj + (size_t)(row0 + rb + 8 * rr) * NROW + jb + jo);
      const uint4* bs = (const uint4*)(WhT + (size_t)bfr * NROW + jb + bj);
      bv0 = bs[0]; bv1 = bs[1];
    }

    // ---- phase 2: MFMA P @ Wh ----
#pragma unroll
    for (int ks = 0; ks < 2; ++ks) {
      const int ko = ks * 32 + (l >> 4) * 8;
      short8 a0 = *(const short8*)&P[(rwave + (l & 15)) * LDP + ko];
      short8 a1 = *(const short8*)&P[(rwave + 16 + (l & 15)) * LDP + ko];
      short8 b0 = *(const short8*)&BT[(nwave + (l & 15)) * LDP + ko];
      short8 b1 = *(const short8*)&BT[(nwave + 16 + (l & 15)) * LDP + ko];
      acc00 = __builtin_amdgcn_mfma_f32_16x16x32_bf16(a0, b0, acc00, 0, 0, 0);
      acc01 = __builtin_amdgcn_mfma_f32_16x16x32_bf16(a0, b1, acc01, 0, 0, 0);
      acc10 = __builtin_amdgcn_mfma_f32_16x16x32_bf16(a1, b0, acc10, 0, 0, 0);
      acc11 = __builtin_amdgcn_mfma_f32_16x16x32_bf16(a1, b1, acc11, 0, 0, 0);
    }
    __syncthreads();
  }

  // ---- Z: reduce each row's partial over its 32-lane half-wave ----
#pragma unroll
  for (int rr = 0; rr < 8; ++rr) {
    float z = zacc[rr];
#pragma unroll
    for (int mk = 16; mk; mk >>= 1) z += __shfl_xor(z, mk, 64);
    if ((l & 31) == 0) Zp[(size_t)blockIdx.x * 64 + rb + 8 * rr] = z;
  }

  // ---- store partial acc tile [64x64] ----
  float* ab = accp + (size_t)blockIdx.x * 4096;
  {
    const int rbase = (l >> 4) * 4;
    const int cbase = l & 15;
#pragma unroll
    for (int rg = 0; rg < 4; ++rg) {
      ab[(rwave + rbase + rg) * 64 + (nwave + cbase)] = acc00[rg];
      ab[(rwave + rbase + rg) * 64 + (nwave + 16 + cbase)] = acc01[rg];
      ab[(rwave + 16 + rbase + rg) * 64 + (nwave + cbase)] = acc10[rg];
      ab[(rwave + 16 + rbase + rg) * 64 + (nwave + 16 + cbase)] = acc11[rg];
    }
  }
}

// ---------------- Kernel 4: combine partials, normalize, elu ----------------
__global__ __launch_bounds__(256) void k_combine(const float* __restrict__ accp,
                                                 const float* __restrict__ Zp,
                                                 float* __restrict__ out,
                                                 int splits) {
  const int idx = blockIdx.x * 256 + threadIdx.x;
  const int r = idx >> 6, f = idx & 63;
  const int tile = r >> 6, rl = r & 63;
  float sum = 0.f, z = 0.f;
  for (int sp = 0; sp < splits; ++sp) {
    const int b = tile * splits + sp;
    sum += accp[(size_t)b * 4096 + rl * 64 + f];
    z += Zp[(size_t)b * 64 + rl];
  }
  const float v = sum / z;
  out[idx] = (v > 0.f) ? v : expm1f(v);
}

extern "C" void kernel_launch(void* const* d_in, const int* in_sizes, int n_in,
                              void* d_out, int out_size, void* d_ws, size_t ws_size,
                              hipStream_t stream) {
  const float* h = (const float*)d_in[0];
  const int* adj = (const int*)d_in[1];
  const float* W = (const float*)d_in[2];
  const float* a = (const float*)d_in[3];
  float* out = (float*)d_out;

  // workspace layout
  int splits = 8;
  auto need = [](int sp) -> size_t {
    return (size_t)1048576 /*WhT*/ + 65536 /*s,d*/ + 256 /*dmax*/ +
           (size_t)sp * 128 * 64 * 4 /*Zp*/ + (size_t)sp * 128 * 4096 * 4 /*accp*/;
  };
  while (splits > 1 && need(splits) > ws_size) splits >>= 1;

  char* p = (char*)d_ws;
  __hip_bfloat16* WhT = (__hip_bfloat16*)p;
  float* s = (float*)(p + 1048576);
  float* d = (float*)(p + 1048576 + 32768);
  float* dmax = (float*)(p + 1048576 + 65536);
  float* Zp = (float*)(p + 1048576 + 65536 + 256);
  float* accp = (float*)((char*)Zp + (size_t)splits * 128 * 64 * 4);

  hipLaunchKernelGGL(k_wh, dim3(NROW / 4), dim3(256), 0, stream, h, W, a, WhT, s, d);
  hipLaunchKernelGGL(k_dmax, dim3(1), dim3(256), 0, stream, d, dmax);
  hipLaunchKernelGGL(k_main, dim3(128 * splits), dim3(256), 0, stream,
                     adj, WhT, s, d, dmax, accp, Zp, splits);
  hipLaunchKernelGGL(k_combine, dim3(out_size / 256), dim3(256), 0, stream,
                     accp, Zp, out, splits);
}